// Round 2
// baseline (685.341 us; speedup 1.0000x reference)
//
#include <hip/hip_runtime.h>
#include <math.h>

// ---------------- CSR build ----------------

__global__ __launch_bounds__(256) void k_zero(int* __restrict__ counts, int N) {
    int i = blockIdx.x * 256 + threadIdx.x;
    if (i < N) counts[i] = 0;
}

__global__ __launch_bounds__(256) void k_count(const int* __restrict__ dst,
                                               int* __restrict__ counts, int E) {
    int e = blockIdx.x * 256 + threadIdx.x;
    if (e < E) atomicAdd(&counts[dst[e]], 1);
}

__global__ __launch_bounds__(256) void k_dinv(const int* __restrict__ counts,
                                              float* __restrict__ dinv, int N) {
    int i = blockIdx.x * 256 + threadIdx.x;
    if (i < N) dinv[i] = rsqrtf((float)(counts[i] + 1));   // +1 self loop
}

// scan pass 1: per-block (512 elems) exclusive scan, in place over counts->rowstart
__global__ __launch_bounds__(256) void k_scan1(int* __restrict__ rowstart,  // == counts
                                               int* __restrict__ partials, int N) {
    __shared__ int s[256];
    int t = threadIdx.x;
    int base = blockIdx.x * 512;
    int i0 = base + 2 * t, i1 = base + 2 * t + 1;
    int a = (i0 < N) ? rowstart[i0] : 0;
    int b = (i1 < N) ? rowstart[i1] : 0;
    int v = a + b;
    s[t] = v;
    __syncthreads();
    for (int off = 1; off < 256; off <<= 1) {
        int u = (t >= off) ? s[t - off] : 0;
        __syncthreads();
        s[t] += u;
        __syncthreads();
    }
    int excl = s[t] - v;
    if (t == 255) partials[blockIdx.x] = s[t];
    if (i0 < N) rowstart[i0] = excl;
    if (i1 < N) rowstart[i1] = excl + a;
}

// scan pass 2: single block, exclusive scan of block partials (NB <= 256)
__global__ __launch_bounds__(256) void k_scan2(const int* __restrict__ partials,
                                               int* __restrict__ blockoff, int NB) {
    __shared__ int s[256];
    int t = threadIdx.x;
    int v = (t < NB) ? partials[t] : 0;
    s[t] = v;
    __syncthreads();
    for (int off = 1; off < 256; off <<= 1) {
        int u = (t >= off) ? s[t - off] : 0;
        __syncthreads();
        s[t] += u;
        __syncthreads();
    }
    if (t < NB) blockoff[t] = s[t] - v;
}

// scan pass 3: add block offsets, init cursor, set rowstart[N]=E
__global__ __launch_bounds__(256) void k_scan3(int* __restrict__ rowstart,
                                               const int* __restrict__ blockoff,
                                               int* __restrict__ cursor, int N, int E) {
    int i = blockIdx.x * 256 + threadIdx.x;
    if (i < N) {
        int rs = rowstart[i] + blockoff[i >> 9];
        rowstart[i] = rs;
        cursor[i] = rs;
    }
    if (i == 0) rowstart[N] = E;
}

__global__ __launch_bounds__(256) void k_scatter(const int* __restrict__ src,
                                                 const int* __restrict__ dst,
                                                 int* __restrict__ cursor,
                                                 int* __restrict__ csr_src, int E) {
    int e = blockIdx.x * 256 + threadIdx.x;
    if (e >= E) return;
    int pos = atomicAdd(&cursor[dst[e]], 1);
    csr_src[pos] = src[e];
}

// ---------------- layer compute ----------------

// hw1n[i,:] = dinv[i] * (x[i,:] @ W1); 16 rows per 256-thread block
__global__ __launch_bounds__(256) void k_gemm1(const float* __restrict__ x,
                                               const float* __restrict__ W1,
                                               const float* __restrict__ dinv,
                                               float* __restrict__ hw1n, int N) {
    __shared__ float sW[128 * 16];
    __shared__ float sX[16][128];
    int t = threadIdx.x;
    for (int k = t; k < 128 * 16; k += 256) sW[k] = W1[k];
    int row0 = blockIdx.x * 16;
    for (int k = t; k < 16 * 128; k += 256) {
        int r = k >> 7, c = k & 127;
        int gr = row0 + r;
        sX[r][c] = (gr < N) ? x[gr * 128 + c] : 0.f;
    }
    __syncthreads();
    int r = t >> 4, c = t & 15;
    float acc = 0.f;
#pragma unroll 16
    for (int k = 0; k < 128; ++k) acc += sX[r][k] * sW[k * 16 + c];
    int gr = row0 + r;
    if (gr < N) hw1n[gr * 16 + c] = dinv[gr] * acc;
}

// CSR gather-aggregate layer 1 + bias + GEMM2, pre-scaled by dinv:
// h1[i,j] = dinv[i]*(sum_{s in in(i)} hw1n[s,j] + hw1n[i,j]) + b1[j]
// hw2n[i,:] = dinv[i] * (h1[i,:] @ W2)
__global__ __launch_bounds__(256) void k_agg1l2(const int* __restrict__ rowstart,
                                                const int* __restrict__ csr_src,
                                                const float* __restrict__ dinv,
                                                const float* __restrict__ hw1n,
                                                const float* __restrict__ W2,
                                                const float* __restrict__ b1,
                                                float* __restrict__ hw2n, int N) {
    __shared__ float sW[16 * 8];
    __shared__ float sb[16];
    __shared__ float sh[16][17];
    int t = threadIdx.x;
    if (t < 128) sW[t] = W2[t];
    if (t < 16)  sb[t] = b1[t];
    __syncthreads();
    int g = t >> 4, j = t & 15;
    int i = blockIdx.x * 16 + g;
    float h = 0.f;
    float di = 0.f;
    if (i < N) {
        int beg = rowstart[i], end = rowstart[i + 1];
        di = dinv[i];
        for (int e = beg; e < end; ++e) {
            int s = csr_src[e];                  // broadcast across 16 lanes
            h += hw1n[(size_t)s * 16 + j];       // contiguous 64B per group
        }
        h = di * (h + hw1n[(size_t)i * 16 + j]) + sb[j];
    }
    sh[g][j] = h;
    __syncthreads();
    if (i < N && j < 8) {
        float o = 0.f;
#pragma unroll
        for (int k = 0; k < 16; ++k) o += sh[g][k] * sW[k * 8 + j];
        hw2n[(size_t)i * 8 + j] = di * o;
    }
}

// CSR gather-aggregate layer 2 + bias + Wl dot + sigmoid -> z
__global__ __launch_bounds__(256) void k_agg2z(const int* __restrict__ rowstart,
                                               const int* __restrict__ csr_src,
                                               const float* __restrict__ dinv,
                                               const float* __restrict__ hw2n,
                                               const float* __restrict__ Wl,
                                               const float* __restrict__ b2,
                                               const float* __restrict__ bl,
                                               float* __restrict__ z, int N) {
    __shared__ float sW[8], sb[8];
    __shared__ float sbl;
    int t = threadIdx.x;
    if (t < 8) { sW[t] = Wl[t]; sb[t] = b2[t]; }
    if (t == 0) sbl = bl[0];
    __syncthreads();
    int g = t >> 3, j = t & 7;
    int i = blockIdx.x * 32 + g;
    float v = 0.f;
    if (i < N) {
        int beg = rowstart[i], end = rowstart[i + 1];
        float di = dinv[i];
        float h = 0.f;
        for (int e = beg; e < end; ++e) {
            int s = csr_src[e];
            h += hw2n[(size_t)s * 8 + j];
        }
        h = di * (h + hw2n[(size_t)i * 8 + j]) + sb[j];
        v = h * sW[j];
    }
    // 8-lane reduce (groups are 8-aligned within the 64-wide wave)
    v += __shfl_xor(v, 1);
    v += __shfl_xor(v, 2);
    v += __shfl_xor(v, 4);
    if (i < N && j == 0) z[i] = 1.f / (1.f + __expf(-(v + sbl)));
}

__global__ __launch_bounds__(256) void k_pred(const int* __restrict__ pe,
                                              const float* __restrict__ z,
                                              float* __restrict__ out, int P) {
    int p = blockIdx.x * 256 + threadIdx.x;
    if (p < P) out[p] = z[pe[2 * p]] * z[pe[2 * p + 1]];
}

// ---------------- launch ----------------

extern "C" void kernel_launch(void* const* d_in, const int* in_sizes, int n_in,
                              void* d_out, int out_size, void* d_ws, size_t ws_size,
                              hipStream_t stream) {
    const float* x  = (const float*)d_in[0];
    const int*   ei = (const int*)d_in[1];
    const int*   pe = (const int*)d_in[2];
    const float* W1 = (const float*)d_in[3];
    const float* b1 = (const float*)d_in[4];
    const float* W2 = (const float*)d_in[5];
    const float* b2 = (const float*)d_in[6];
    const float* Wl = (const float*)d_in[7];
    const float* bl = (const float*)d_in[8];
    float* out = (float*)d_out;

    const int N = in_sizes[0] / 128;
    const int E = in_sizes[1] / 2;
    const int P = in_sizes[2] / 2;

    const int* src = ei;
    const int* dst = ei + E;

    // workspace layout (4-byte words), overlapping lifetimes:
    //   dinv     [0, N)
    //   hw1n     [N, 17N)
    //   hw2n     [17N, 25N)
    //   rowstart [25N, 26N+1)   (doubles as counts before the scan)
    //   cursor   [26N+1, 27N+1) (doubles as z after scatter is done)
    //   partials [27N+1, +256), blockoff next 256
    //   csr_src  [.., +E)
    float* ws = (float*)d_ws;
    float* dinv     = ws;
    float* hw1n     = ws + (size_t)N;
    float* hw2n     = ws + (size_t)17 * N;
    int*   rowstart = (int*)(ws + (size_t)25 * N);     // N+1 entries (== counts)
    int*   cursor   = (int*)(ws + (size_t)26 * N + 1); // N entries
    float* z        = (float*)cursor;                  // reuse after scatter
    int*   partials = (int*)(ws + (size_t)27 * N + 1);
    int*   blockoff = partials + 256;
    int*   csr_src  = blockoff + 256;

    const int B = 256;
    const int NB = (N + 511) / 512;   // scan blocks (<=256 for N<=131072)

    k_zero <<<(N + B - 1) / B, B, 0, stream>>>(rowstart, N);
    k_count<<<(E + B - 1) / B, B, 0, stream>>>(dst, rowstart, E);
    k_dinv <<<(N + B - 1) / B, B, 0, stream>>>(rowstart, dinv, N);
    k_gemm1<<<(N + 15) / 16, B, 0, stream>>>(x, W1, dinv, hw1n, N);
    k_scan1<<<NB, B, 0, stream>>>(rowstart, partials, N);
    k_scan2<<<1, B, 0, stream>>>(partials, blockoff, NB);
    k_scan3<<<(N + B - 1) / B, B, 0, stream>>>(rowstart, blockoff, cursor, N, E);
    k_scatter<<<(E + B - 1) / B, B, 0, stream>>>(src, dst, cursor, csr_src, E);
    k_agg1l2<<<(N + 15) / 16, B, 0, stream>>>(rowstart, csr_src, dinv, hw1n, W2, b1, hw2n, N);
    k_agg2z<<<(N + 31) / 32, B, 0, stream>>>(rowstart, csr_src, dinv, hw2n, Wl, b2, bl, z, N);
    k_pred <<<(P + B - 1) / B, B, 0, stream>>>(pe, z, out, P);
}